// Round 24
// baseline (238.422 us; speedup 1.0000x reference)
//
#include <hip/hip_runtime.h>
#include <hip/hip_bf16.h>

// ---------------------------------------------------------------------------
// TileSelfAttention, round 24.
// GEMM: barrier ladder completed: 1 barrier per chunk.  All 8 stages for
//   chunk kc+1 issued at top of chunk kc; single VMC(8)+BAR retires chunk
//   kc's stages (kc+1's stay in flight).  Reads wait-free within the chunk.
// Everything else frozen: K/Q/V bf16, logits MFMA, no-max softmax,
//   split out_kernel.
// ---------------------------------------------------------------------------

typedef __bf16 bf16;
using i32x4  = __attribute__((ext_vector_type(4))) int;
using bf16x8 = __attribute__((ext_vector_type(8))) __bf16;
using f32x4  = __attribute__((ext_vector_type(4))) float;

#define NT     64
#define BATCH  512

#define OFF_XQH 0ul
#define OFF_XQL 33554432ul
#define OFF_WT  67108864ul
#define OFF_K   70254592ul          // bf16
#define OFF_Q   103809024ul         // bf16
#define OFF_V   137363456ul         // bf16
#define OFF_AW  204472320ul         // fp32 E values
#define OFF_MS  212860928ul         // I table (16KB)

// ---------------------------------------------------------------------------
__global__ void quant_all(const float* __restrict__ x,
                          unsigned int* __restrict__ qh,
                          unsigned int* __restrict__ ql, float invXS,
                          const float* __restrict__ W0,
                          const float* __restrict__ W1,
                          const float* __restrict__ W2,
                          char* __restrict__ WT, float invWS) {
  if (blockIdx.x < 2048) {
    int i = blockIdx.x * 256 + threadIdx.x;
    for (; i < 8388608; i += 2048 * 256) {
      float4 v = ((const float4*)x)[i];
      unsigned hw = 0, lw = 0;
#pragma unroll
      for (int j = 0; j < 4; ++j) {
        float f = (j == 0) ? v.x : (j == 1) ? v.y : (j == 2) ? v.z : v.w;
        int q = __float2int_rn(f * invXS);
        q = max(-16320, min(16319, q));
        int h = (q + 64) >> 7;
        int lo = q - (h << 7);
        hw |= ((unsigned)(h & 0xFF)) << (8 * j);
        lw |= ((unsigned)(lo & 0xFF)) << (8 * j);
      }
      qh[i] = hw;
      ql[i] = lw;
    }
  } else {
    int gid = (blockIdx.x - 2048) * 256 + threadIdx.x;  // 0..393215
    int proj = gid >> 17;
    int idx = gid & 131071;
    const float* W = (proj == 0) ? W0 : (proj == 1 ? W1 : W2);
    int c = idx >> 8, k = (idx & 255) * 4;
    float4 v = ((const float4*)W)[idx];
    unsigned hw = 0, lw = 0;
#pragma unroll
    for (int j = 0; j < 4; ++j) {
      float f = (j == 0) ? v.x : (j == 1) ? v.y : (j == 2) ? v.z : v.w;
      int q = __float2int_rn(f * invWS);
      q = max(-16320, min(16319, q));
      int h = (q + 64) >> 7;
      int lo = q - (h << 7);
      hw |= ((unsigned)(h & 0xFF)) << (8 * j);
      lw |= ((unsigned)(lo & 0xFF)) << (8 * j);
    }
    int kc = k >> 6, kg = (k >> 4) & 3, ki = k & 15;
    int ct = c >> 4, lane = (c & 15) | (kg << 4);
    size_t dst = (size_t)proj * 1048576 + (size_t)(ct * 16 + kc) * 2048 +
                 lane * 16 + ki;
    *(unsigned int*)(WT + dst) = hw;          // ph plane
    *(unsigned int*)(WT + dst + 1024) = lw;   // pl plane
  }
}

// ---------------------------------------------------------------------------
__device__ __forceinline__ void gl16(const char* g, char* l) {
  __builtin_amdgcn_global_load_lds(
      (const __attribute__((address_space(1))) unsigned int*)g,
      (__attribute__((address_space(3))) unsigned int*)l, 16, 0, 0);
}

#define VMC(n)  asm volatile("s_waitcnt vmcnt(" #n ")" ::: "memory")
#define BAR     __builtin_amdgcn_s_barrier()
#define MFMA8   __builtin_amdgcn_mfma_i32_16x16x64_i8

__global__ __launch_bounds__(512, 2) void gemm_i8(
    const char* __restrict__ XQH, const char* __restrict__ XQL,
    const char* __restrict__ WT,
    const float* __restrict__ bk, const float* __restrict__ bq,
    const float* __restrict__ bv,
    bf16* __restrict__ K, bf16* __restrict__ Q, bf16* __restrict__ V) {
  __shared__ __align__(16) char lds[131072];  // 2 x 64KB
  // buffer: Aqh [0,16K) Aql [16K,32K) Bph [32K,48K) Bpl [48K,64K)

  const int bid = (blockIdx.x & 7) * 96 + (blockIdx.x >> 3);
  const int mt = bid / 6, nb = bid % 6;
  const int gm0 = mt * 256;
  const int proj = nb >> 1;
  const int nbl = nb & 1;
  const int wn0 = nbl * 256;

  const int tid = threadIdx.x;
  const int l = tid & 63, w = tid >> 6;
  const int wr = w >> 2, wc = w & 3;   // 8 waves: 2M x 4N, wave tile 128x64
  const int lr = l & 15, lk = l >> 4;

  const char* aqh0 = XQH + (size_t)(gm0 + ((tid >> 6) << 4) + (tid & 15)) * 1024
                         + (((tid >> 4) & 3) << 4);
  const char* aql0 = XQL + (size_t)(gm0 + ((tid >> 6) << 4) + (tid & 15)) * 1024
                         + (((tid >> 4) & 3) << 4);
  const char* wph0 = WT + (size_t)proj * 1048576 +
                     (size_t)(nbl * 16 + (tid >> 6)) * 32768 + (tid & 63) * 16;
  const char* wpl0 = wph0 + 1024;
  const int dT = tid * 16;

  const int rdA = (wr * 8) * 1024 + l * 16;          // + mf*1024 ; ql +16384
  const int rdB = 32768 + (wc * 4) * 1024 + l * 16;  // + nf*1024 ; pl +16384

  i32x4 acc[8][4] = {};
  const i32x4 Z = {0, 0, 0, 0};

  auto stageAll = [&](int kc, int bo) {
    const int kA = kc * 64, kB = kc * 2048;
    gl16(aqh0 + kA, lds + bo + dT);
    gl16(aqh0 + 131072 + kA, lds + bo + 8192 + dT);
    gl16(wpl0 + kB, lds + bo + 49152 + dT);
    gl16(wpl0 + 262144 + kB, lds + bo + 57344 + dT);
    gl16(wph0 + kB, lds + bo + 32768 + dT);
    gl16(wph0 + 262144 + kB, lds + bo + 40960 + dT);
    gl16(aql0 + kA, lds + bo + 16384 + dT);
    gl16(aql0 + 131072 + kA, lds + bo + 24576 + dT);
  };

  stageAll(0, 0);

  auto chunk = [&](int kc, bool last) {
    const int bo = (kc & 1) * 65536, nbuf = bo ^ 65536;
    i32x4 aHa[4], aHb[4], aLa[4], aLb[4], bH[4], bL[4];

    // single publish point: stage kc+1, retire kc's 8 stages, one barrier
    if (!last) { stageAll(kc + 1, nbuf); VMC(8); } else { VMC(0); }
    BAR;

    // ---- P1: alpha0 (Aqh[m0-3] . Bpl)
#pragma unroll
    for (int m = 0; m < 4; ++m)
      aHa[m] = *(const i32x4*)(lds + bo + rdA + m * 1024);
#pragma unroll
    for (int n = 0; n < 4; ++n)
      bL[n] = *(const i32x4*)(lds + bo + rdB + 16384 + n * 1024);
    __builtin_amdgcn_s_setprio(1);
#pragma unroll
    for (int m = 0; m < 4; ++m)
#pragma unroll
      for (int n = 0; n < 4; ++n)
        acc[m][n] = MFMA8(aHa[m], bL[n], acc[m][n], 0, 0, 0);
    __builtin_amdgcn_s_setprio(0);

    // ---- P2: alpha1 (Aqh[m4-7] . Bpl)
#pragma unroll
    for (int m = 0; m < 4; ++m)
      aHb[m] = *(const i32x4*)(lds + bo + rdA + (m + 4) * 1024);
    __builtin_amdgcn_s_setprio(1);
#pragma unroll
    for (int m = 0; m < 4; ++m)
#pragma unroll
      for (int n = 0; n < 4; ++n)
        acc[m + 4][n] = MFMA8(aHb[m], bL[n], acc[m + 4][n], 0, 0, 0);
    __builtin_amdgcn_s_setprio(0);

    // ---- P3: beta1 (Aqh[m4-7] . Bph) << 7
#pragma unroll
    for (int n = 0; n < 4; ++n)
      bH[n] = *(const i32x4*)(lds + bo + rdB + n * 1024);
    __builtin_amdgcn_s_setprio(1);
#pragma unroll
    for (int n = 0; n < 4; ++n) {
      i32x4 t0 = MFMA8(aHb[0], bH[n], Z, 0, 0, 0);
      i32x4 t1 = MFMA8(aHb[1], bH[n], Z, 0, 0, 0);
      i32x4 t2 = MFMA8(aHb[2], bH[n], Z, 0, 0, 0);
      i32x4 t3 = MFMA8(aHb[3], bH[n], Z, 0, 0, 0);
      acc[4][n] = acc[4][n] + (t0 << 7);
      acc[5][n] = acc[5][n] + (t1 << 7);
      acc[6][n] = acc[6][n] + (t2 << 7);
      acc[7][n] = acc[7][n] + (t3 << 7);
    }
    __builtin_amdgcn_s_setprio(0);

    // ---- P4: beta0 (Aqh[m0-3] . Bph) << 7
#pragma unroll
    for (int m = 0; m < 4; ++m)
      aLa[m] = *(const i32x4*)(lds + bo + 16384 + rdA + m * 1024);
    __builtin_amdgcn_s_setprio(1);
#pragma unroll
    for (int n = 0; n < 4; ++n) {
      i32x4 t0 = MFMA8(aHa[0], bH[n], Z, 0, 0, 0);
      i32x4 t1 = MFMA8(aHa[1], bH[n], Z, 0, 0, 0);
      i32x4 t2 = MFMA8(aHa[2], bH[n], Z, 0, 0, 0);
      i32x4 t3 = MFMA8(aHa[3], bH[n], Z, 0, 0, 0);
      acc[0][n] = acc[0][n] + (t0 << 7);
      acc[1][n] = acc[1][n] + (t1 << 7);
      acc[2][n] = acc[2][n] + (t2 << 7);
      acc[3][n] = acc[3][n] + (t3 << 7);
    }
    __builtin_amdgcn_s_setprio(0);

    // ---- P5: gamma0 (Aql[m0-3] . Bph)
#pragma unroll
    for (int m = 0; m < 4; ++m)
      aLb[m] = *(const i32x4*)(lds + bo + 16384 + rdA + (m + 4) * 1024);
    __builtin_amdgcn_s_setprio(1);
#pragma unroll
    for (int m = 0; m < 4; ++m)
#pragma unroll
      for (int n = 0; n < 4; ++n)
        acc[m][n] = MFMA8(aLa[m], bH[n], acc[m][n], 0, 0, 0);
    __builtin_amdgcn_s_setprio(0);

    // ---- P6: gamma1 (Aql[m4-7] . Bph)
    __builtin_amdgcn_s_setprio(1);
#pragma unroll
    for (int m = 0; m < 4; ++m)
#pragma unroll
      for (int n = 0; n < 4; ++n)
        acc[m + 4][n] = MFMA8(aLb[m], bH[n], acc[m + 4][n], 0, 0, 0);
    __builtin_amdgcn_s_setprio(0);
  };

  for (int kc = 0; kc < 15; ++kc) chunk(kc, false);
  chunk(15, true);

  // epilogue: Out = 128*SC*acc + bias; K,Q,V all stored bf16
  const float SCC = 128.0f * (6.0f / 16256.0f) * (0.03125f / 16320.0f);
  const float* bias = (proj == 0) ? bk : (proj == 1 ? bq : bv);
  bf16* Ob = (proj == 0) ? K : (proj == 1 ? Q : V);
#pragma unroll
  for (int m = 0; m < 8; ++m) {
    const int row0 = gm0 + wr * 128 + m * 16 + lk * 4;
#pragma unroll
    for (int n = 0; n < 4; ++n) {
      const int col = wn0 + wc * 64 + n * 16 + lr;
      const float bb = bias[col];
#pragma unroll
      for (int r = 0; r < 4; ++r)
        Ob[(size_t)(row0 + r) * 512 + col] =
            (bf16)(SCC * (float)acc[m][n][r] + bb);
    }
  }
}

// ---------------------------------------------------------------------------
// logits (MFMA): E[b,t,s] = exp(scale * sum_c K[b*64+t,c]*Q[b*64+s,c])
// ---------------------------------------------------------------------------
__global__ __launch_bounds__(256) void logits_kernel(
    const bf16* __restrict__ K, const bf16* __restrict__ Q,
    float* __restrict__ E) {
  __shared__ __align__(16) char lds[131072];  // K [0,64K), Q [64K,128K)
  const int b = blockIdx.x;
  const int tid = threadIdx.x;
  const int l = tid & 63, w = tid >> 6;

  const char* Kb = (const char*)(K + (size_t)b * 32768);
  const char* Qb = (const char*)(Q + (size_t)b * 32768);
  const size_t so = (size_t)((tid >> 6) * 16 + (l & 15)) * 1024 +
                    ((l >> 4) * 8) * 2;
  const int dT = tid * 16;
#pragma unroll
  for (int j = 0; j < 16; ++j) {
    gl16(Kb + so + j * 64, lds + j * 4096 + dT);
    gl16(Qb + so + j * 64, lds + 65536 + j * 4096 + dT);
  }
  VMC(0);
  BAR;

  f32x4 acc[4] = {};
  for (int ks = 0; ks < 16; ++ks) {
    bf16x8 bF = *(const bf16x8*)(lds + 65536 + (ks * 4 + w) * 1024 + l * 16);
#pragma unroll
    for (int m = 0; m < 4; ++m) {
      bf16x8 aF = *(const bf16x8*)(lds + (ks * 4 + m) * 1024 + l * 16);
      acc[m] = __builtin_amdgcn_mfma_f32_16x16x32_bf16(aF, bF, acc[m], 0, 0, 0);
    }
  }

  const float scale = 0.04419417382415922f;
  float* Eb = E + (size_t)b * 4096;
  const int s = w * 16 + (l & 15);
  const int r0 = (l >> 4) * 4;
#pragma unroll
  for (int m = 0; m < 4; ++m)
#pragma unroll
    for (int r = 0; r < 4; ++r)
      Eb[(m * 16 + r0 + r) * 64 + s] = __expf(acc[m][r] * scale);
}

// ---------------------------------------------------------------------------
// sums over batch axis: I[t,s] = 1 / sum_b E[b,t,s]
// ---------------------------------------------------------------------------
__global__ __launch_bounds__(1024) void sums_kernel(
    const float* __restrict__ E, float* __restrict__ I) {
  __shared__ float red[16][64];
  const int tt = blockIdx.x;
  const int tid = threadIdx.x;
  const int s = tid & 63, bq = tid >> 6;
  const size_t base = (size_t)tt * 64 + s;

  float sum = 0.f;
  for (int b = bq * 32; b < bq * 32 + 32; ++b)
    sum += E[(size_t)b * 4096 + base];
  red[bq][s] = sum;
  __syncthreads();
  if (bq == 0) {
    float total = 0.f;
#pragma unroll
    for (int i = 0; i < 16; ++i) total += red[i][s];
    I[tt * 64 + s] = 1.0f / total;
  }
}

// ---------------------------------------------------------------------------
// out[b,c,s] = sum_t V[b*64+t, c] * (E[b,t,s] * I[t,s])
// ---------------------------------------------------------------------------
__global__ __launch_bounds__(512) void out_kernel(
    const bf16* __restrict__ V, const float* __restrict__ E,
    const float* __restrict__ I, float* __restrict__ out) {
  __shared__ float Vs[16384];    // [t][c-half 256] flat fp32, 64KB
  __shared__ float Ps[64][64];   // 16.38KB
  const int bid = blockIdx.x;
  const int b = bid >> 1, half = bid & 1;
  const int tid = threadIdx.x;
  const unsigned short* Vb =
      (const unsigned short*)(V + (size_t)b * 32768 + half * 256);
  const float* Eb = E + (size_t)b * 4096;

#pragma unroll
  for (int j = 0; j < 8; ++j) {
    int u = j * 512 + tid;           // float4 unit: t = u>>6, c4 = u&63
    int t = u >> 6, c4 = u & 63;
    uint2 raw = *(const uint2*)(Vb + (size_t)t * 512 + c4 * 4);
    float4 f;
    f.x = __uint_as_float(raw.x << 16);
    f.y = __uint_as_float(raw.x & 0xffff0000u);
    f.z = __uint_as_float(raw.y << 16);
    f.w = __uint_as_float(raw.y & 0xffff0000u);
    ((float4*)Vs)[t * 64 + c4] = f;
  }
  for (int i = tid; i < 4096; i += 512)
    Ps[i >> 6][i & 63] = Eb[i] * I[i];
  __syncthreads();

  const int s = tid & 63, cw = tid >> 6;  // cw 0..7
  const int c0 = cw * 32;
  float a[32] = {};
  for (int t = 0; t < 64; ++t) {
    float p = Ps[t][s];
    const float4* vr = (const float4*)(Vs + t * 256 + c0);
#pragma unroll
    for (int j = 0; j < 8; ++j) {
      float4 v = vr[j];
      a[4 * j + 0] += v.x * p;
      a[4 * j + 1] += v.y * p;
      a[4 * j + 2] += v.z * p;
      a[4 * j + 3] += v.w * p;
    }
  }
  float* Ob = out + (size_t)b * 32768 + (size_t)(half * 256 + c0) * 64;
#pragma unroll
  for (int j = 0; j < 32; ++j)
    Ob[(size_t)j * 64 + s] = a[j];
}

// ---------------------------------------------------------------------------
extern "C" void kernel_launch(void* const* d_in, const int* in_sizes, int n_in,
                              void* d_out, int out_size, void* d_ws,
                              size_t ws_size, hipStream_t stream) {
  const float* x  = (const float*)d_in[0];
  const float* Wk = (const float*)d_in[1];
  const float* bk = (const float*)d_in[2];
  const float* Wq = (const float*)d_in[3];
  const float* bq = (const float*)d_in[4];
  const float* Wv = (const float*)d_in[5];
  const float* bv = (const float*)d_in[6];
  float* out = (float*)d_out;

  char* ws = (char*)d_ws;
  unsigned int* XQH = (unsigned int*)(ws + OFF_XQH);
  unsigned int* XQL = (unsigned int*)(ws + OFF_XQL);
  char* WT = ws + OFF_WT;
  bf16* K  = (bf16*)(ws + OFF_K);
  bf16* Q  = (bf16*)(ws + OFF_Q);
  bf16* V  = (bf16*)(ws + OFF_V);
  float* E  = (float*)(ws + OFF_AW);
  float* I  = (float*)(ws + OFF_MS);

  const float invXS = 16256.0f / 6.0f;
  const float invWS = 16320.0f / 0.03125f;

  quant_all<<<3584, 256, 0, stream>>>(x, XQH, XQL, invXS, Wk, Wq, Wv, WT,
                                      invWS);

  gemm_i8<<<768, 512, 0, stream>>>((const char*)XQH, (const char*)XQL,
                                   WT, bk, bq, bv, K, Q, V);

  logits_kernel<<<BATCH, 256, 0, stream>>>(K, Q, E);
  sums_kernel<<<NT, 1024, 0, stream>>>(E, I);
  out_kernel<<<BATCH * 2, 512, 0, stream>>>(V, E, I, out);
}

// Round 25
// 234.950 us; speedup vs baseline: 1.0148x; 1.0148x over previous
//
#include <hip/hip_runtime.h>
#include <hip/hip_bf16.h>

// ---------------------------------------------------------------------------
// TileSelfAttention, round 25 = revert to R23 optimum (best: 234.4us).
// GEMM: 2 barriers/chunk (merged publish at P2: prev Bph+Aql via VMC(4);
//   P5 publishes next Aqh+Bpl).  1-barrier variant (R24) regressed.
// K/Q/V bf16, logits MFMA, no-max softmax, split out_kernel (2 blocks/CU).
// ---------------------------------------------------------------------------

typedef __bf16 bf16;
using i32x4  = __attribute__((ext_vector_type(4))) int;
using bf16x8 = __attribute__((ext_vector_type(8))) __bf16;
using f32x4  = __attribute__((ext_vector_type(4))) float;

#define NT     64
#define BATCH  512

#define OFF_XQH 0ul
#define OFF_XQL 33554432ul
#define OFF_WT  67108864ul
#define OFF_K   70254592ul          // bf16
#define OFF_Q   103809024ul         // bf16
#define OFF_V   137363456ul         // bf16
#define OFF_AW  204472320ul         // fp32 E values
#define OFF_MS  212860928ul         // I table (16KB)

// ---------------------------------------------------------------------------
__global__ void quant_all(const float* __restrict__ x,
                          unsigned int* __restrict__ qh,
                          unsigned int* __restrict__ ql, float invXS,
                          const float* __restrict__ W0,
                          const float* __restrict__ W1,
                          const float* __restrict__ W2,
                          char* __restrict__ WT, float invWS) {
  if (blockIdx.x < 2048) {
    int i = blockIdx.x * 256 + threadIdx.x;
    for (; i < 8388608; i += 2048 * 256) {
      float4 v = ((const float4*)x)[i];
      unsigned hw = 0, lw = 0;
#pragma unroll
      for (int j = 0; j < 4; ++j) {
        float f = (j == 0) ? v.x : (j == 1) ? v.y : (j == 2) ? v.z : v.w;
        int q = __float2int_rn(f * invXS);
        q = max(-16320, min(16319, q));
        int h = (q + 64) >> 7;
        int lo = q - (h << 7);
        hw |= ((unsigned)(h & 0xFF)) << (8 * j);
        lw |= ((unsigned)(lo & 0xFF)) << (8 * j);
      }
      qh[i] = hw;
      ql[i] = lw;
    }
  } else {
    int gid = (blockIdx.x - 2048) * 256 + threadIdx.x;  // 0..393215
    int proj = gid >> 17;
    int idx = gid & 131071;
    const float* W = (proj == 0) ? W0 : (proj == 1 ? W1 : W2);
    int c = idx >> 8, k = (idx & 255) * 4;
    float4 v = ((const float4*)W)[idx];
    unsigned hw = 0, lw = 0;
#pragma unroll
    for (int j = 0; j < 4; ++j) {
      float f = (j == 0) ? v.x : (j == 1) ? v.y : (j == 2) ? v.z : v.w;
      int q = __float2int_rn(f * invWS);
      q = max(-16320, min(16319, q));
      int h = (q + 64) >> 7;
      int lo = q - (h << 7);
      hw |= ((unsigned)(h & 0xFF)) << (8 * j);
      lw |= ((unsigned)(lo & 0xFF)) << (8 * j);
    }
    int kc = k >> 6, kg = (k >> 4) & 3, ki = k & 15;
    int ct = c >> 4, lane = (c & 15) | (kg << 4);
    size_t dst = (size_t)proj * 1048576 + (size_t)(ct * 16 + kc) * 2048 +
                 lane * 16 + ki;
    *(unsigned int*)(WT + dst) = hw;          // ph plane
    *(unsigned int*)(WT + dst + 1024) = lw;   // pl plane
  }
}

// ---------------------------------------------------------------------------
__device__ __forceinline__ void gl16(const char* g, char* l) {
  __builtin_amdgcn_global_load_lds(
      (const __attribute__((address_space(1))) unsigned int*)g,
      (__attribute__((address_space(3))) unsigned int*)l, 16, 0, 0);
}

#define VMC(n)  asm volatile("s_waitcnt vmcnt(" #n ")" ::: "memory")
#define BAR     __builtin_amdgcn_s_barrier()
#define MFMA8   __builtin_amdgcn_mfma_i32_16x16x64_i8

__global__ __launch_bounds__(512, 2) void gemm_i8(
    const char* __restrict__ XQH, const char* __restrict__ XQL,
    const char* __restrict__ WT,
    const float* __restrict__ bk, const float* __restrict__ bq,
    const float* __restrict__ bv,
    bf16* __restrict__ K, bf16* __restrict__ Q, bf16* __restrict__ V) {
  __shared__ __align__(16) char lds[131072];  // 2 x 64KB
  // buffer: Aqh [0,16K) Aql [16K,32K) Bph [32K,48K) Bpl [48K,64K)

  const int bid = (blockIdx.x & 7) * 96 + (blockIdx.x >> 3);
  const int mt = bid / 6, nb = bid % 6;
  const int gm0 = mt * 256;
  const int proj = nb >> 1;
  const int nbl = nb & 1;
  const int wn0 = nbl * 256;

  const int tid = threadIdx.x;
  const int l = tid & 63, w = tid >> 6;
  const int wr = w >> 2, wc = w & 3;   // 8 waves: 2M x 4N, wave tile 128x64
  const int lr = l & 15, lk = l >> 4;

  const char* aqh0 = XQH + (size_t)(gm0 + ((tid >> 6) << 4) + (tid & 15)) * 1024
                         + (((tid >> 4) & 3) << 4);
  const char* aql0 = XQL + (size_t)(gm0 + ((tid >> 6) << 4) + (tid & 15)) * 1024
                         + (((tid >> 4) & 3) << 4);
  const char* wph0 = WT + (size_t)proj * 1048576 +
                     (size_t)(nbl * 16 + (tid >> 6)) * 32768 + (tid & 63) * 16;
  const char* wpl0 = wph0 + 1024;
  const int dT = tid * 16;

  const int rdA = (wr * 8) * 1024 + l * 16;          // + mf*1024 ; ql +16384
  const int rdB = 32768 + (wc * 4) * 1024 + l * 16;  // + nf*1024 ; pl +16384

  i32x4 acc[8][4] = {};
  const i32x4 Z = {0, 0, 0, 0};

  auto stAqh = [&](int kc, int bo) {
    const int kA = kc * 64;
    gl16(aqh0 + kA, lds + bo + dT);
    gl16(aqh0 + 131072 + kA, lds + bo + 8192 + dT);
  };
  auto stAql = [&](int kc, int bo) {
    const int kA = kc * 64;
    gl16(aql0 + kA, lds + bo + 16384 + dT);
    gl16(aql0 + 131072 + kA, lds + bo + 24576 + dT);
  };
  auto stBph = [&](int kc, int bo) {
    const int kB = kc * 2048;
    gl16(wph0 + kB, lds + bo + 32768 + dT);
    gl16(wph0 + 262144 + kB, lds + bo + 40960 + dT);
  };
  auto stBpl = [&](int kc, int bo) {
    const int kB = kc * 2048;
    gl16(wpl0 + kB, lds + bo + 49152 + dT);
    gl16(wpl0 + 262144 + kB, lds + bo + 57344 + dT);
  };

  stAqh(0, 0); stBpl(0, 0); stBph(0, 0); stAql(0, 0);
  VMC(4);   // retire Aqh(0)+Bpl(0); Bph(0),Aql(0) stay in flight
  BAR;

  auto chunk = [&](int kc, bool last) {
    const int bo = (kc & 1) * 65536, nbuf = bo ^ 65536;
    i32x4 aHa[4], aHb[4], aLa[4], aLb[4], bH[4], bL[4];

    // ---- P1: reads Aqh[m0-3], Bpl (published @ prev P5); stage next Aqh
#pragma unroll
    for (int m = 0; m < 4; ++m)
      aHa[m] = *(const i32x4*)(lds + bo + rdA + m * 1024);
#pragma unroll
    for (int n = 0; n < 4; ++n)
      bL[n] = *(const i32x4*)(lds + bo + rdB + 16384 + n * 1024);
    if (!last) stAqh(kc + 1, nbuf);
    __builtin_amdgcn_s_setprio(1);
#pragma unroll
    for (int m = 0; m < 4; ++m)
#pragma unroll
      for (int n = 0; n < 4; ++n)
        acc[m][n] = MFMA8(aHa[m], bL[n], acc[m][n], 0, 0, 0);
    __builtin_amdgcn_s_setprio(0);

    // ---- P2: reads Aqh[m4-7]; stage next Bpl; MERGED PUBLISH Bph+Aql(bo)
#pragma unroll
    for (int m = 0; m < 4; ++m)
      aHb[m] = *(const i32x4*)(lds + bo + rdA + (m + 4) * 1024);
    if (!last) { stBpl(kc + 1, nbuf); VMC(4); } else { VMC(0); }
    BAR;
    __builtin_amdgcn_s_setprio(1);
#pragma unroll
    for (int m = 0; m < 4; ++m)
#pragma unroll
      for (int n = 0; n < 4; ++n)
        acc[m + 4][n] = MFMA8(aHb[m], bL[n], acc[m + 4][n], 0, 0, 0);
    __builtin_amdgcn_s_setprio(0);

    // ---- P3: reads Bph (published @ P2); stage next Bph; no wait
#pragma unroll
    for (int n = 0; n < 4; ++n)
      bH[n] = *(const i32x4*)(lds + bo + rdB + n * 1024);
    if (!last) stBph(kc + 1, nbuf);
    __builtin_amdgcn_s_setprio(1);
#pragma unroll
    for (int n = 0; n < 4; ++n) {
      i32x4 t0 = MFMA8(aHb[0], bH[n], Z, 0, 0, 0);
      i32x4 t1 = MFMA8(aHb[1], bH[n], Z, 0, 0, 0);
      i32x4 t2 = MFMA8(aHb[2], bH[n], Z, 0, 0, 0);
      i32x4 t3 = MFMA8(aHb[3], bH[n], Z, 0, 0, 0);
      acc[4][n] = acc[4][n] + (t0 << 7);
      acc[5][n] = acc[5][n] + (t1 << 7);
      acc[6][n] = acc[6][n] + (t2 << 7);
      acc[7][n] = acc[7][n] + (t3 << 7);
    }
    __builtin_amdgcn_s_setprio(0);

    // ---- P4: reads Aql[m0-3] (published @ P2); stage next Aql; no wait
#pragma unroll
    for (int m = 0; m < 4; ++m)
      aLa[m] = *(const i32x4*)(lds + bo + 16384 + rdA + m * 1024);
    if (!last) stAql(kc + 1, nbuf);
    __builtin_amdgcn_s_setprio(1);
#pragma unroll
    for (int n = 0; n < 4; ++n) {
      i32x4 t0 = MFMA8(aHa[0], bH[n], Z, 0, 0, 0);
      i32x4 t1 = MFMA8(aHa[1], bH[n], Z, 0, 0, 0);
      i32x4 t2 = MFMA8(aHa[2], bH[n], Z, 0, 0, 0);
      i32x4 t3 = MFMA8(aHa[3], bH[n], Z, 0, 0, 0);
      acc[0][n] = acc[0][n] + (t0 << 7);
      acc[1][n] = acc[1][n] + (t1 << 7);
      acc[2][n] = acc[2][n] + (t2 << 7);
      acc[3][n] = acc[3][n] + (t3 << 7);
    }
    __builtin_amdgcn_s_setprio(0);

    // ---- P5: reads Aql[m4-7]; PUBLISH next chunk's Aqh+Bpl
#pragma unroll
    for (int m = 0; m < 4; ++m)
      aLb[m] = *(const i32x4*)(lds + bo + 16384 + rdA + (m + 4) * 1024);
    if (!last) { VMC(4); BAR; }
    __builtin_amdgcn_s_setprio(1);
#pragma unroll
    for (int m = 0; m < 4; ++m)
#pragma unroll
      for (int n = 0; n < 4; ++n)
        acc[m][n] = MFMA8(aLa[m], bH[n], acc[m][n], 0, 0, 0);
    __builtin_amdgcn_s_setprio(0);

    // ---- P6: register-only
    __builtin_amdgcn_s_setprio(1);
#pragma unroll
    for (int m = 0; m < 4; ++m)
#pragma unroll
      for (int n = 0; n < 4; ++n)
        acc[m + 4][n] = MFMA8(aLb[m], bH[n], acc[m + 4][n], 0, 0, 0);
    __builtin_amdgcn_s_setprio(0);
  };

  for (int kc = 0; kc < 15; ++kc) chunk(kc, false);
  chunk(15, true);

  // epilogue: Out = 128*SC*acc + bias; K,Q,V all stored bf16
  const float SCC = 128.0f * (6.0f / 16256.0f) * (0.03125f / 16320.0f);
  const float* bias = (proj == 0) ? bk : (proj == 1 ? bq : bv);
  bf16* Ob = (proj == 0) ? K : (proj == 1 ? Q : V);
#pragma unroll
  for (int m = 0; m < 8; ++m) {
    const int row0 = gm0 + wr * 128 + m * 16 + lk * 4;
#pragma unroll
    for (int n = 0; n < 4; ++n) {
      const int col = wn0 + wc * 64 + n * 16 + lr;
      const float bb = bias[col];
#pragma unroll
      for (int r = 0; r < 4; ++r)
        Ob[(size_t)(row0 + r) * 512 + col] =
            (bf16)(SCC * (float)acc[m][n][r] + bb);
    }
  }
}

// ---------------------------------------------------------------------------
// logits (MFMA): E[b,t,s] = exp(scale * sum_c K[b*64+t,c]*Q[b*64+s,c])
// ---------------------------------------------------------------------------
__global__ __launch_bounds__(256) void logits_kernel(
    const bf16* __restrict__ K, const bf16* __restrict__ Q,
    float* __restrict__ E) {
  __shared__ __align__(16) char lds[131072];  // K [0,64K), Q [64K,128K)
  const int b = blockIdx.x;
  const int tid = threadIdx.x;
  const int l = tid & 63, w = tid >> 6;

  const char* Kb = (const char*)(K + (size_t)b * 32768);
  const char* Qb = (const char*)(Q + (size_t)b * 32768);
  const size_t so = (size_t)((tid >> 6) * 16 + (l & 15)) * 1024 +
                    ((l >> 4) * 8) * 2;
  const int dT = tid * 16;
#pragma unroll
  for (int j = 0; j < 16; ++j) {
    gl16(Kb + so + j * 64, lds + j * 4096 + dT);
    gl16(Qb + so + j * 64, lds + 65536 + j * 4096 + dT);
  }
  VMC(0);
  BAR;

  f32x4 acc[4] = {};
  for (int ks = 0; ks < 16; ++ks) {
    bf16x8 bF = *(const bf16x8*)(lds + 65536 + (ks * 4 + w) * 1024 + l * 16);
#pragma unroll
    for (int m = 0; m < 4; ++m) {
      bf16x8 aF = *(const bf16x8*)(lds + (ks * 4 + m) * 1024 + l * 16);
      acc[m] = __builtin_amdgcn_mfma_f32_16x16x32_bf16(aF, bF, acc[m], 0, 0, 0);
    }
  }

  const float scale = 0.04419417382415922f;
  float* Eb = E + (size_t)b * 4096;
  const int s = w * 16 + (l & 15);
  const int r0 = (l >> 4) * 4;
#pragma unroll
  for (int m = 0; m < 4; ++m)
#pragma unroll
    for (int r = 0; r < 4; ++r)
      Eb[(m * 16 + r0 + r) * 64 + s] = __expf(acc[m][r] * scale);
}

// ---------------------------------------------------------------------------
// sums over batch axis: I[t,s] = 1 / sum_b E[b,t,s]
// ---------------------------------------------------------------------------
__global__ __launch_bounds__(1024) void sums_kernel(
    const float* __restrict__ E, float* __restrict__ I) {
  __shared__ float red[16][64];
  const int tt = blockIdx.x;
  const int tid = threadIdx.x;
  const int s = tid & 63, bq = tid >> 6;
  const size_t base = (size_t)tt * 64 + s;

  float sum = 0.f;
  for (int b = bq * 32; b < bq * 32 + 32; ++b)
    sum += E[(size_t)b * 4096 + base];
  red[bq][s] = sum;
  __syncthreads();
  if (bq == 0) {
    float total = 0.f;
#pragma unroll
    for (int i = 0; i < 16; ++i) total += red[i][s];
    I[tt * 64 + s] = 1.0f / total;
  }
}

// ---------------------------------------------------------------------------
// out[b,c,s] = sum_t V[b*64+t, c] * (E[b,t,s] * I[t,s])
// ---------------------------------------------------------------------------
__global__ __launch_bounds__(512) void out_kernel(
    const bf16* __restrict__ V, const float* __restrict__ E,
    const float* __restrict__ I, float* __restrict__ out) {
  __shared__ float Vs[16384];    // [t][c-half 256] flat fp32, 64KB
  __shared__ float Ps[64][64];   // 16.38KB
  const int bid = blockIdx.x;
  const int b = bid >> 1, half = bid & 1;
  const int tid = threadIdx.x;
  const unsigned short* Vb =
      (const unsigned short*)(V + (size_t)b * 32768 + half * 256);
  const float* Eb = E + (size_t)b * 4096;

#pragma unroll
  for (int j = 0; j < 8; ++j) {
    int u = j * 512 + tid;           // float4 unit: t = u>>6, c4 = u&63
    int t = u >> 6, c4 = u & 63;
    uint2 raw = *(const uint2*)(Vb + (size_t)t * 512 + c4 * 4);
    float4 f;
    f.x = __uint_as_float(raw.x << 16);
    f.y = __uint_as_float(raw.x & 0xffff0000u);
    f.z = __uint_as_float(raw.y << 16);
    f.w = __uint_as_float(raw.y & 0xffff0000u);
    ((float4*)Vs)[t * 64 + c4] = f;
  }
  for (int i = tid; i < 4096; i += 512)
    Ps[i >> 6][i & 63] = Eb[i] * I[i];
  __syncthreads();

  const int s = tid & 63, cw = tid >> 6;  // cw 0..7
  const int c0 = cw * 32;
  float a[32] = {};
  for (int t = 0; t < 64; ++t) {
    float p = Ps[t][s];
    const float4* vr = (const float4*)(Vs + t * 256 + c0);
#pragma unroll
    for (int j = 0; j < 8; ++j) {
      float4 v = vr[j];
      a[4 * j + 0] += v.x * p;
      a[4 * j + 1] += v.y * p;
      a[4 * j + 2] += v.z * p;
      a[4 * j + 3] += v.w * p;
    }
  }
  float* Ob = out + (size_t)b * 32768 + (size_t)(half * 256 + c0) * 64;
#pragma unroll
  for (int j = 0; j < 32; ++j)
    Ob[(size_t)j * 64 + s] = a[j];
}

// ---------------------------------------------------------------------------
extern "C" void kernel_launch(void* const* d_in, const int* in_sizes, int n_in,
                              void* d_out, int out_size, void* d_ws,
                              size_t ws_size, hipStream_t stream) {
  const float* x  = (const float*)d_in[0];
  const float* Wk = (const float*)d_in[1];
  const float* bk = (const float*)d_in[2];
  const float* Wq = (const float*)d_in[3];
  const float* bq = (const float*)d_in[4];
  const float* Wv = (const float*)d_in[5];
  const float* bv = (const float*)d_in[6];
  float* out = (float*)d_out;

  char* ws = (char*)d_ws;
  unsigned int* XQH = (unsigned int*)(ws + OFF_XQH);
  unsigned int* XQL = (unsigned int*)(ws + OFF_XQL);
  char* WT = ws + OFF_WT;
  bf16* K  = (bf16*)(ws + OFF_K);
  bf16* Q  = (bf16*)(ws + OFF_Q);
  bf16* V  = (bf16*)(ws + OFF_V);
  float* E  = (float*)(ws + OFF_AW);
  float* I  = (float*)(ws + OFF_MS);

  const float invXS = 16256.0f / 6.0f;
  const float invWS = 16320.0f / 0.03125f;

  quant_all<<<3584, 256, 0, stream>>>(x, XQH, XQL, invXS, Wk, Wq, Wv, WT,
                                      invWS);

  gemm_i8<<<768, 512, 0, stream>>>((const char*)XQH, (const char*)XQL,
                                   WT, bk, bq, bv, K, Q, V);

  logits_kernel<<<BATCH, 256, 0, stream>>>(K, Q, E);
  sums_kernel<<<NT, 1024, 0, stream>>>(E, I);
  out_kernel<<<BATCH * 2, 512, 0, stream>>>(V, E, I, out);
}